// Round 1
// baseline (139617.700 us; speedup 1.0000x reference)
//
#include <hip/hip_runtime.h>

// ---------------- problem constants ----------------
#define T_STEPS 1000
#define BATCH   128
#define HID     256
#define G4      1024    // 4*HID
#define INSZ    2
#define NOUT    100     // OUT*K
#define NW      20      // K mixture weights
#define BT      4       // batch rows per workgroup
#define NTH     512     // threads per workgroup

// ws (scratch) layout in floats: transposed weights + combined biases
constexpr int OFF_WT0  = 0;                       // W_hh0^T   [256][1024]
constexpr int OFF_WX0  = OFF_WT0  + 256 * 1024;   // W_ih0^T   [2][1024]
constexpr int OFF_WTI1 = OFF_WX0  + 2   * 1024;   // W_ih[0]^T [258][1024]
constexpr int OFF_WTH1 = OFF_WTI1 + 258 * 1024;   // W_hh[0]^T [256][1024]
constexpr int OFF_WTI2 = OFF_WTH1 + 256 * 1024;   // W_ih[1]^T [258][1024]
constexpr int OFF_WTH2 = OFF_WTI2 + 258 * 1024;   // W_hh[1]^T [256][1024]
constexpr int OFF_B    = OFF_WTH2 + 256 * 1024;   // bsum0|bsum1|bsum2 [3*1024]
constexpr int WS_FLOATS = OFF_B + 3 * 1024;       // 1,319,936 floats (~5.28 MB)

__device__ __forceinline__ float sigf(float x)      { return 1.0f / (1.0f + __expf(-x)); }
__device__ __forceinline__ float tanhfast(float x)  { return 2.0f / (1.0f + __expf(-2.0f * x)) - 1.0f; }

// dst[C][R] = src[R][C]^T ; writes coalesced
__global__ void transpose_f32(const float* __restrict__ src, float* __restrict__ dst,
                              int R, int C) {
    int total = R * C;
    for (int idx = blockIdx.x * blockDim.x + threadIdx.x; idx < total;
         idx += gridDim.x * blockDim.x) {
        int c = idx / R;          // R is a power of two (1024) in all calls
        int r = idx - c * R;
        dst[idx] = src[r * C + c];
    }
}

__global__ void add_vec(const float* __restrict__ a, const float* __restrict__ b,
                        float* __restrict__ dst, int n) {
    int i = blockIdx.x * blockDim.x + threadIdx.x;
    if (i < n) dst[i] = a[i] + b[i];
}

// Accumulate acc{0,1}[r] += sum_k h[r][k] * W(kOff+k, j{0,1}) over k in [0,HID)
// PRE:  W is transposed  -> W[(kOff+k)*G4 + j]   (lane-coalesced)
// !PRE: W is row-major   -> W[j*ld + kOff + k]   (per-lane stream)
template <bool PRE>
__device__ __forceinline__ void gate_accum(float* acc0, float* acc1,
                                           const float* hbase,   // LDS [BT][HID]
                                           const float* __restrict__ W,
                                           int j0, int j1, int ld, int kOff) {
#pragma unroll 2
    for (int k = 0; k < HID; k += 4) {
        float4 hv[BT];
#pragma unroll
        for (int r = 0; r < BT; ++r)
            hv[r] = *reinterpret_cast<const float4*>(hbase + r * HID + k);
#pragma unroll
        for (int kk = 0; kk < 4; ++kk) {
            float w0, w1;
            if (PRE) {
                w0 = W[(kOff + k + kk) * G4 + j0];
                w1 = W[(kOff + k + kk) * G4 + j1];
            } else {
                w0 = W[j0 * ld + kOff + k + kk];
                w1 = W[j1 * ld + kOff + k + kk];
            }
#pragma unroll
            for (int r = 0; r < BT; ++r) {
                float hk = reinterpret_cast<const float*>(&hv[r])[kk];
                acc0[r] = fmaf(hk, w0, acc0[r]);
                acc1[r] = fmaf(hk, w1, acc1[r]);
            }
        }
    }
}

__device__ __forceinline__ void lstm_update(const float (*gS)[G4], float (*hS)[HID],
                                            float (*cS)[HID], int tid) {
#pragma unroll
    for (int p = 0; p < 2; ++p) {
        int task = tid + p * NTH;          // BT*HID = 1024 tasks
        int n = task & (HID - 1);
        int r = task >> 8;
        float gi = gS[r][n];
        float gf = gS[r][HID + n];
        float gg = gS[r][2 * HID + n];
        float go = gS[r][3 * HID + n];
        float c  = sigf(gf) * cS[r][n] + sigf(gi) * tanhfast(gg);
        float h  = sigf(go) * tanhfast(c);
        cS[r][n] = c;
        hS[r][n] = h;
    }
}

template <bool PRE>
__global__ __launch_bounds__(NTH)
void lstm_main(const float* __restrict__ x,       // [128][1000][2]
               const float* __restrict__ Wih0,    // [1024][2]
               const float* __restrict__ Whh0,    // [1024][256]
               const float* __restrict__ bih0, const float* __restrict__ bhh0,
               const float* __restrict__ WihL,    // [2][1024][258]
               const float* __restrict__ WhhL,    // [2][1024][256]
               const float* __restrict__ bihL, const float* __restrict__ bhhL,
               const float* __restrict__ Wg, const float* __restrict__ bg,   // [100][258],[100]
               const float* __restrict__ Ww, const float* __restrict__ bw,   // [20][258],[20]
               const float* __restrict__ ws,
               float* __restrict__ out) {
    __shared__ float h_s[3][BT][HID];
    __shared__ float c_s[3][BT][HID];
    __shared__ float g_s[BT][G4];
    __shared__ float x_s[BT][INSZ];
    __shared__ float wl_s[BT][NW];

    const int tid = threadIdx.x;
    const int b0  = blockIdx.x * BT;
    const int j0  = tid;
    const int j1  = tid + NTH;

    // zero initial state
    for (int i = tid; i < 3 * BT * HID; i += NTH) {
        (&h_s[0][0][0])[i] = 0.0f;
        (&c_s[0][0][0])[i] = 0.0f;
    }
    __syncthreads();

    const float* Wt0  = ws + OFF_WT0;
    const float* Wx0  = ws + OFF_WX0;
    const float* Wti1 = ws + OFF_WTI1;
    const float* Wth1 = ws + OFF_WTH1;
    const float* Wti2 = ws + OFF_WTI2;
    const float* Wth2 = ws + OFF_WTH2;
    const float* bs   = ws + OFF_B;

    constexpr size_t GOFF = (size_t)BATCH * T_STEPS * NOUT;   // start of ws output

    for (int t = 0; t < T_STEPS; ++t) {
        if (tid < BT * INSZ) {
            int r = tid >> 1, k = tid & 1;
            x_s[r][k] = x[((size_t)(b0 + r) * T_STEPS + t) * INSZ + k];
        }
        __syncthreads();

        // ---------------- layer 0 ----------------
        {
            float acc0[BT], acc1[BT];
            float bb0, bb1;
            if (PRE) { bb0 = bs[j0]; bb1 = bs[j1]; }
            else     { bb0 = bih0[j0] + bhh0[j0]; bb1 = bih0[j1] + bhh0[j1]; }
#pragma unroll
            for (int r = 0; r < BT; ++r) { acc0[r] = bb0; acc1[r] = bb1; }
#pragma unroll
            for (int k = 0; k < INSZ; ++k) {
                float w0 = PRE ? Wx0[k * G4 + j0] : Wih0[j0 * INSZ + k];
                float w1 = PRE ? Wx0[k * G4 + j1] : Wih0[j1 * INSZ + k];
#pragma unroll
                for (int r = 0; r < BT; ++r) {
                    acc0[r] = fmaf(x_s[r][k], w0, acc0[r]);
                    acc1[r] = fmaf(x_s[r][k], w1, acc1[r]);
                }
            }
            gate_accum<PRE>(acc0, acc1, &h_s[0][0][0],
                            PRE ? Wt0 : Whh0, j0, j1, HID, 0);
#pragma unroll
            for (int r = 0; r < BT; ++r) { g_s[r][j0] = acc0[r]; g_s[r][j1] = acc1[r]; }
        }
        __syncthreads();
        lstm_update(g_s, h_s[0], c_s[0], tid);
        __syncthreads();

        // ---------------- layers 1,2 ----------------
#pragma unroll
        for (int l = 1; l <= 2; ++l) {
            const float* WtiP = (l == 1) ? Wti1 : Wti2;
            const float* WthP = (l == 1) ? Wth1 : Wth2;
            const float* WihD = WihL + (size_t)(l - 1) * G4 * (INSZ + HID);
            const float* WhhD = WhhL + (size_t)(l - 1) * G4 * HID;

            float acc0[BT], acc1[BT];
            float bb0, bb1;
            if (PRE) { bb0 = bs[l * G4 + j0]; bb1 = bs[l * G4 + j1]; }
            else {
                bb0 = bihL[(l - 1) * G4 + j0] + bhhL[(l - 1) * G4 + j0];
                bb1 = bihL[(l - 1) * G4 + j1] + bhhL[(l - 1) * G4 + j1];
            }
#pragma unroll
            for (int r = 0; r < BT; ++r) { acc0[r] = bb0; acc1[r] = bb1; }
#pragma unroll
            for (int k = 0; k < INSZ; ++k) {
                float w0 = PRE ? WtiP[k * G4 + j0] : WihD[j0 * (INSZ + HID) + k];
                float w1 = PRE ? WtiP[k * G4 + j1] : WihD[j1 * (INSZ + HID) + k];
#pragma unroll
                for (int r = 0; r < BT; ++r) {
                    acc0[r] = fmaf(x_s[r][k], w0, acc0[r]);
                    acc1[r] = fmaf(x_s[r][k], w1, acc1[r]);
                }
            }
            // skip-connection part: h of layer below (rows 2..257 of W_ih)
            gate_accum<PRE>(acc0, acc1, &h_s[l - 1][0][0],
                            PRE ? WtiP : WihD, j0, j1, INSZ + HID, INSZ);
            // recurrent part
            gate_accum<PRE>(acc0, acc1, &h_s[l][0][0],
                            PRE ? WthP : WhhD, j0, j1, HID, 0);
#pragma unroll
            for (int r = 0; r < BT; ++r) { g_s[r][j0] = acc0[r]; g_s[r][j1] = acc1[r]; }
            __syncthreads();
            lstm_update(g_s, h_s[l], c_s[l], tid);
            __syncthreads();
        }

        // ---------------- output head ----------------
        if (tid < BT * (NOUT + NW)) {              // 480 threads
            int r  = tid / (NOUT + NW);
            int jo = tid - r * (NOUT + NW);
            const float* Wrow;
            float acc;
            if (jo < NOUT) { Wrow = Wg + (size_t)jo * (INSZ + HID); acc = bg[jo]; }
            else           { Wrow = Ww + (size_t)(jo - NOUT) * (INSZ + HID); acc = bw[jo - NOUT]; }
            acc = fmaf(x_s[r][0], Wrow[0], acc);
            acc = fmaf(x_s[r][1], Wrow[1], acc);
            const float* hr = &h_s[2][r][0];
#pragma unroll 4
            for (int k = 0; k < HID; k += 2) {
                float2 w2 = *reinterpret_cast<const float2*>(Wrow + INSZ + k);  // 8B aligned
                float2 h2 = *reinterpret_cast<const float2*>(hr + k);
                acc = fmaf(h2.x, w2.x, acc);
                acc = fmaf(h2.y, w2.y, acc);
            }
            if (jo < NOUT)
                out[((size_t)(b0 + r) * T_STEPS + t) * NOUT + jo] = acc;
            else
                wl_s[r][jo - NOUT] = acc;
        }
        __syncthreads();

        if (tid < BT) {   // softmax over the 20 mixture logits, one row per thread
            int r = tid;
            float mx = -1e30f;
#pragma unroll
            for (int m = 0; m < NW; ++m) mx = fmaxf(mx, wl_s[r][m]);
            float e[NW];
            float ssum = 0.0f;
#pragma unroll
            for (int m = 0; m < NW; ++m) { e[m] = __expf(wl_s[r][m] - mx); ssum += e[m]; }
            float inv = 1.0f / ssum;
            size_t base = GOFF + ((size_t)(b0 + r) * T_STEPS + t) * NW;
#pragma unroll
            for (int m = 0; m < NW; ++m) out[base + m] = e[m] * inv;
        }
        __syncthreads();   // protect x_s / wl_s / h_s reuse next step
    }
}

extern "C" void kernel_launch(void* const* d_in, const int* in_sizes, int n_in,
                              void* d_out, int out_size, void* d_ws, size_t ws_size,
                              hipStream_t stream) {
    const float* x    = (const float*)d_in[0];
    const float* Wih0 = (const float*)d_in[1];
    const float* Whh0 = (const float*)d_in[2];
    const float* bih0 = (const float*)d_in[3];
    const float* bhh0 = (const float*)d_in[4];
    const float* WihL = (const float*)d_in[5];
    const float* WhhL = (const float*)d_in[6];
    const float* bihL = (const float*)d_in[7];
    const float* bhhL = (const float*)d_in[8];
    const float* Wg   = (const float*)d_in[9];
    const float* bg   = (const float*)d_in[10];
    const float* Ww   = (const float*)d_in[11];
    const float* bw   = (const float*)d_in[12];
    float* out = (float*)d_out;
    float* wsf = (float*)d_ws;

    (void)in_sizes; (void)n_in; (void)out_size;

    const bool pre = (ws_size >= (size_t)WS_FLOATS * sizeof(float));

    if (pre) {
        transpose_f32<<<512, 256, 0, stream>>>(Whh0, wsf + OFF_WT0, G4, HID);
        transpose_f32<<<8,   256, 0, stream>>>(Wih0, wsf + OFF_WX0, G4, INSZ);
        transpose_f32<<<512, 256, 0, stream>>>(WihL,                     wsf + OFF_WTI1, G4, INSZ + HID);
        transpose_f32<<<512, 256, 0, stream>>>(WhhL,                     wsf + OFF_WTH1, G4, HID);
        transpose_f32<<<512, 256, 0, stream>>>(WihL + (size_t)G4 * (INSZ + HID), wsf + OFF_WTI2, G4, INSZ + HID);
        transpose_f32<<<512, 256, 0, stream>>>(WhhL + (size_t)G4 * HID,          wsf + OFF_WTH2, G4, HID);
        add_vec<<<4, 256, 0, stream>>>(bih0, bhh0, wsf + OFF_B, G4);
        add_vec<<<4, 256, 0, stream>>>(bihL, bhhL, wsf + OFF_B + G4, G4);
        add_vec<<<4, 256, 0, stream>>>(bihL + G4, bhhL + G4, wsf + OFF_B + 2 * G4, G4);
        lstm_main<true><<<BATCH / BT, NTH, 0, stream>>>(
            x, Wih0, Whh0, bih0, bhh0, WihL, WhhL, bihL, bhhL, Wg, bg, Ww, bw, wsf, out);
    } else {
        lstm_main<false><<<BATCH / BT, NTH, 0, stream>>>(
            x, Wih0, Whh0, bih0, bhh0, WihL, WhhL, bihL, bhhL, Wg, bg, Ww, bw, wsf, out);
    }
}

// Round 2
// 24698.489 us; speedup vs baseline: 5.6529x; 5.6529x over previous
//
#include <hip/hip_runtime.h>
#include <hip/hip_fp16.h>
#include <stdint.h>

// ---------------- problem constants ----------------
#define T_STEPS 1000
#define BATCH   128
#define HID     256
#define G4      1024    // 4*HID
#define INSZ    2
#define NOUT    100     // OUT*K
#define NW      20      // K mixture weights

// ---- fp16 packed-weight main path ----
#define BT2     2       // batch rows per workgroup
#define NTH     512
#define WPDW    (32 * G4 * 4)   // dwords per packed matrix (K=256: 32 k8-blocks x 1024 cols x 4 dwords)

constexpr int OFF_P0  = 0;                   // Whh0 packed
constexpr int OFF_PI1 = OFF_P0  + WPDW;      // Wih[0] h-part packed
constexpr int OFF_PH1 = OFF_PI1 + WPDW;      // Whh[0] packed
constexpr int OFF_PI2 = OFF_PH1 + WPDW;      // Wih[1] h-part packed
constexpr int OFF_PH2 = OFF_PI2 + WPDW;      // Whh[1] packed
constexpr int OFF_X   = OFF_PH2 + WPDW;      // fp32 x-part weights [3][2][1024]
constexpr int OFF_B   = OFF_X + 3 * 2 * G4;  // fp32 combined biases [3][1024]
constexpr int WS_DWORDS = OFF_B + 3 * G4;    // ~664,576 dwords = 2.66 MB

__device__ __forceinline__ float sigf(float x)     { return 1.0f / (1.0f + __expf(-x)); }
__device__ __forceinline__ float tanhfast(float x) { return 2.0f / (1.0f + __expf(-2.0f * x)) - 1.0f; }

typedef _Float16 h2v __attribute__((ext_vector_type(2)));

__device__ __forceinline__ float dot2f(uint32_t w, uint32_t h, float acc) {
    return __builtin_amdgcn_fdot2(__builtin_bit_cast(h2v, w),
                                  __builtin_bit_cast(h2v, h), acc, false);
}

// ---------------- prep kernels ----------------
// Pack W[j][colOff+k] (row-major, ld) -> dst[(k>>3)*4096 + j*4 + ((k>>1)&3)] as half2(k, k+1)
__global__ void pack_w16(const float* __restrict__ src, uint32_t* __restrict__ dst,
                         int ld, int colOff) {
    int id = blockIdx.x * blockDim.x + threadIdx.x;   // 0..131071
    int kp = id & 127;          // k-pair index
    int j  = id >> 7;           // gate col 0..1023
    int k  = kp * 2;
    float a = src[(size_t)j * ld + colOff + k];
    float b = src[(size_t)j * ld + colOff + k + 1];
    __half2 hv = __floats2half2_rn(a, b);
    dst[(k >> 3) * (G4 * 4) + j * 4 + ((k >> 1) & 3)] = *reinterpret_cast<uint32_t*>(&hv);
}

// transpose the 2-column x-part: dst[k*1024 + j] = src[j*ld + k], k in {0,1}
__global__ void xpart_t(const float* __restrict__ src, float* __restrict__ dst, int ld) {
    int id = blockIdx.x * blockDim.x + threadIdx.x;   // 0..2047
    int k = id >> 10;
    int j = id & 1023;
    dst[k * G4 + j] = src[(size_t)j * ld + k];
}

__global__ void add_vec(const float* __restrict__ a, const float* __restrict__ b,
                        float* __restrict__ dst, int n) {
    int i = blockIdx.x * blockDim.x + threadIdx.x;
    if (i < n) dst[i] = a[i] + b[i];
}

// ---------------- fp16 dot2 gate accumulation ----------------
// acc[col][row]; Wp = packed matrix base; hb0/hb1 = LDS fp16 h rows (as dwords)
__device__ __forceinline__ void accum_mat(float& a00, float& a01, float& a10, float& a11,
                                          const uint32_t* __restrict__ Wp,
                                          const uint32_t* hb0, const uint32_t* hb1, int j0) {
    const uint32_t* w0p = Wp + j0 * 4;
    const uint32_t* w1p = Wp + (j0 + NTH) * 4;
#pragma unroll 4
    for (int k8 = 0; k8 < 32; ++k8) {
        uint4 w0 = *reinterpret_cast<const uint4*>(w0p + k8 * 4096);
        uint4 w1 = *reinterpret_cast<const uint4*>(w1p + k8 * 4096);
        uint4 h0 = *reinterpret_cast<const uint4*>(hb0 + k8 * 4);
        uint4 h1 = *reinterpret_cast<const uint4*>(hb1 + k8 * 4);
        a00 = dot2f(w0.x, h0.x, a00); a00 = dot2f(w0.y, h0.y, a00);
        a00 = dot2f(w0.z, h0.z, a00); a00 = dot2f(w0.w, h0.w, a00);
        a01 = dot2f(w0.x, h1.x, a01); a01 = dot2f(w0.y, h1.y, a01);
        a01 = dot2f(w0.z, h1.z, a01); a01 = dot2f(w0.w, h1.w, a01);
        a10 = dot2f(w1.x, h0.x, a10); a10 = dot2f(w1.y, h0.y, a10);
        a10 = dot2f(w1.z, h0.z, a10); a10 = dot2f(w1.w, h0.w, a10);
        a11 = dot2f(w1.x, h1.x, a11); a11 = dot2f(w1.y, h1.y, a11);
        a11 = dot2f(w1.z, h1.z, a11); a11 = dot2f(w1.w, h1.w, a11);
    }
}

// ---------------- main fp16 kernel: 64 WGs x 512 threads, BT2=2 rows each ----------------
__global__ __launch_bounds__(NTH)
void lstm_main16(const float* __restrict__ x,
                 const float* __restrict__ Wg, const float* __restrict__ bg,
                 const float* __restrict__ Ww, const float* __restrict__ bw,
                 const uint32_t* __restrict__ wp,
                 float* __restrict__ out) {
    __shared__ __align__(16) __half h_h[3][BT2][HID];   // fp16 hidden state
    __shared__ float h2f[BT2][HID];                     // fp32 copy of top h for head
    __shared__ float c_s[3][BT2][HID];
    __shared__ float g_s[BT2][G4];
    __shared__ float x_s[BT2][INSZ];
    __shared__ float wl_s[BT2][NW];

    const int tid = threadIdx.x;
    const int b0  = blockIdx.x * BT2;
    const int j0  = tid;

    for (int i = tid; i < 3 * BT2 * HID; i += NTH) {
        (&h_h[0][0][0])[i] = __float2half(0.0f);
        (&c_s[0][0][0])[i] = 0.0f;
    }
    if (tid < BT2 * INSZ) {
        int r = tid >> 1, k = tid & 1;
        x_s[r][k] = x[((size_t)(b0 + r) * T_STEPS + 0) * INSZ + k];
    }
    __syncthreads();

    const uint32_t* P0  = wp + OFF_P0;
    const uint32_t* PI1 = wp + OFF_PI1;
    const uint32_t* PH1 = wp + OFF_PH1;
    const uint32_t* PI2 = wp + OFF_PI2;
    const uint32_t* PH2 = wp + OFF_PH2;
    const float*    Wxf = (const float*)(wp + OFF_X);
    const float*    bs  = (const float*)(wp + OFF_B);

    constexpr size_t GOFF = (size_t)BATCH * T_STEPS * NOUT;

    for (int t = 0; t < T_STEPS; ++t) {
        const uint32_t* hb[3];
        hb[0] = reinterpret_cast<const uint32_t*>(&h_h[0][0][0]);
        hb[1] = reinterpret_cast<const uint32_t*>(&h_h[1][0][0]);
        hb[2] = reinterpret_cast<const uint32_t*>(&h_h[2][0][0]);
        constexpr int HROW = HID / 2;   // dwords per h row

        // ---------- layer 0 gates ----------
        {
            float a00 = bs[j0], a10 = bs[j0 + NTH];
            float a01 = a00,    a11 = a10;
#pragma unroll
            for (int k = 0; k < INSZ; ++k) {
                float w0 = Wxf[k * G4 + j0];
                float w1 = Wxf[k * G4 + j0 + NTH];
                a00 = fmaf(x_s[0][k], w0, a00); a01 = fmaf(x_s[1][k], w0, a01);
                a10 = fmaf(x_s[0][k], w1, a10); a11 = fmaf(x_s[1][k], w1, a11);
            }
            accum_mat(a00, a01, a10, a11, P0, hb[0], hb[0] + HROW, j0);
            g_s[0][j0] = a00; g_s[1][j0] = a01;
            g_s[0][j0 + NTH] = a10; g_s[1][j0 + NTH] = a11;
        }
        __syncthreads();
        {   // update 0
            int n = tid & (HID - 1), r = tid >> 8;
            float gi = g_s[r][n], gf = g_s[r][n + HID], gg = g_s[r][n + 2 * HID], go = g_s[r][n + 3 * HID];
            float c = sigf(gf) * c_s[0][r][n] + sigf(gi) * tanhfast(gg);
            float h = sigf(go) * tanhfast(c);
            c_s[0][r][n] = c;
            h_h[0][r][n] = __float2half(h);
        }
        __syncthreads();

        // ---------- layers 1,2 ----------
#pragma unroll
        for (int l = 1; l <= 2; ++l) {
            const uint32_t* PI = (l == 1) ? PI1 : PI2;
            const uint32_t* PH = (l == 1) ? PH1 : PH2;
            float a00 = bs[l * G4 + j0], a10 = bs[l * G4 + j0 + NTH];
            float a01 = a00,             a11 = a10;
#pragma unroll
            for (int k = 0; k < INSZ; ++k) {
                float w0 = Wxf[l * 2 * G4 + k * G4 + j0];
                float w1 = Wxf[l * 2 * G4 + k * G4 + j0 + NTH];
                a00 = fmaf(x_s[0][k], w0, a00); a01 = fmaf(x_s[1][k], w0, a01);
                a10 = fmaf(x_s[0][k], w1, a10); a11 = fmaf(x_s[1][k], w1, a11);
            }
            // skip connection over h[l-1], then recurrent over h[l]
            accum_mat(a00, a01, a10, a11, PI, hb[l - 1], hb[l - 1] + HROW, j0);
            accum_mat(a00, a01, a10, a11, PH, hb[l],     hb[l]     + HROW, j0);
            g_s[0][j0] = a00; g_s[1][j0] = a01;
            g_s[0][j0 + NTH] = a10; g_s[1][j0 + NTH] = a11;
            __syncthreads();
            {   // update l
                int n = tid & (HID - 1), r = tid >> 8;
                float gi = g_s[r][n], gf = g_s[r][n + HID], gg = g_s[r][n + 2 * HID], go = g_s[r][n + 3 * HID];
                float c = sigf(gf) * c_s[l][r][n] + sigf(gi) * tanhfast(gg);
                float h = sigf(go) * tanhfast(c);
                c_s[l][r][n] = c;
                h_h[l][r][n] = __float2half(h);
                if (l == 2) h2f[r][n] = h;
            }
            __syncthreads();
        }

        // ---------- output head (fp32) ----------
        if (tid < BT2 * (NOUT + NW)) {   // 240 threads
            int r  = tid / (NOUT + NW);
            int jo = tid - r * (NOUT + NW);
            const float* Wrow;
            float acc;
            if (jo < NOUT) { Wrow = Wg + (size_t)jo * (INSZ + HID); acc = bg[jo]; }
            else           { Wrow = Ww + (size_t)(jo - NOUT) * (INSZ + HID); acc = bw[jo - NOUT]; }
            acc = fmaf(x_s[r][0], Wrow[0], acc);
            acc = fmaf(x_s[r][1], Wrow[1], acc);
            const float* hr = &h2f[r][0];
#pragma unroll 4
            for (int k = 0; k < HID; k += 2) {
                float2 w2 = *reinterpret_cast<const float2*>(Wrow + INSZ + k);
                float2 h2 = *reinterpret_cast<const float2*>(hr + k);
                acc = fmaf(h2.x, w2.x, acc);
                acc = fmaf(h2.y, w2.y, acc);
            }
            if (jo < NOUT)
                out[((size_t)(b0 + r) * T_STEPS + t) * NOUT + jo] = acc;
            else
                wl_s[r][jo - NOUT] = acc;
        }
        __syncthreads();

        // ---------- softmax + x prefetch ----------
        if (tid < BT2) {
            int r = tid;
            float mx = -1e30f;
#pragma unroll
            for (int m = 0; m < NW; ++m) mx = fmaxf(mx, wl_s[r][m]);
            float e[NW]; float ssum = 0.0f;
#pragma unroll
            for (int m = 0; m < NW; ++m) { e[m] = __expf(wl_s[r][m] - mx); ssum += e[m]; }
            float inv = 1.0f / ssum;
            size_t base = GOFF + ((size_t)(b0 + r) * T_STEPS + t) * NW;
#pragma unroll
            for (int m = 0; m < NW; ++m) out[base + m] = e[m] * inv;
        } else if (tid >= 64 && tid < 64 + BT2 * INSZ && t + 1 < T_STEPS) {
            int id = tid - 64;
            int r = id >> 1, k = id & 1;
            x_s[r][k] = x[((size_t)(b0 + r) * T_STEPS + (t + 1)) * INSZ + k];
        }
        __syncthreads();
    }
}

// ---------------- fp32 fallback (round-1 non-PRE path, known-good) ----------------
#define BTF 4
__device__ __forceinline__ void gate_accum_f32(float* acc0, float* acc1,
                                               const float* hbase,
                                               const float* __restrict__ W,
                                               int j0, int j1, int ld, int kOff) {
#pragma unroll 2
    for (int k = 0; k < HID; k += 4) {
        float4 hv[BTF];
#pragma unroll
        for (int r = 0; r < BTF; ++r)
            hv[r] = *reinterpret_cast<const float4*>(hbase + r * HID + k);
#pragma unroll
        for (int kk = 0; kk < 4; ++kk) {
            float w0 = W[j0 * ld + kOff + k + kk];
            float w1 = W[j1 * ld + kOff + k + kk];
#pragma unroll
            for (int r = 0; r < BTF; ++r) {
                float hk = reinterpret_cast<const float*>(&hv[r])[kk];
                acc0[r] = fmaf(hk, w0, acc0[r]);
                acc1[r] = fmaf(hk, w1, acc1[r]);
            }
        }
    }
}

__global__ __launch_bounds__(NTH)
void lstm_main_f32(const float* __restrict__ x,
                   const float* __restrict__ Wih0, const float* __restrict__ Whh0,
                   const float* __restrict__ bih0, const float* __restrict__ bhh0,
                   const float* __restrict__ WihL, const float* __restrict__ WhhL,
                   const float* __restrict__ bihL, const float* __restrict__ bhhL,
                   const float* __restrict__ Wg, const float* __restrict__ bg,
                   const float* __restrict__ Ww, const float* __restrict__ bw,
                   float* __restrict__ out) {
    __shared__ float h_s[3][BTF][HID];
    __shared__ float c_s[3][BTF][HID];
    __shared__ float g_s[BTF][G4];
    __shared__ float x_s[BTF][INSZ];
    __shared__ float wl_s[BTF][NW];

    const int tid = threadIdx.x;
    const int b0  = blockIdx.x * BTF;
    const int j0  = tid;
    const int j1  = tid + NTH;

    for (int i = tid; i < 3 * BTF * HID; i += NTH) {
        (&h_s[0][0][0])[i] = 0.0f;
        (&c_s[0][0][0])[i] = 0.0f;
    }
    __syncthreads();

    constexpr size_t GOFF = (size_t)BATCH * T_STEPS * NOUT;

    for (int t = 0; t < T_STEPS; ++t) {
        if (tid < BTF * INSZ) {
            int r = tid >> 1, k = tid & 1;
            x_s[r][k] = x[((size_t)(b0 + r) * T_STEPS + t) * INSZ + k];
        }
        __syncthreads();
        {
            float acc0[BTF], acc1[BTF];
            float bb0 = bih0[j0] + bhh0[j0], bb1 = bih0[j1] + bhh0[j1];
#pragma unroll
            for (int r = 0; r < BTF; ++r) { acc0[r] = bb0; acc1[r] = bb1; }
#pragma unroll
            for (int k = 0; k < INSZ; ++k) {
                float w0 = Wih0[j0 * INSZ + k], w1 = Wih0[j1 * INSZ + k];
#pragma unroll
                for (int r = 0; r < BTF; ++r) {
                    acc0[r] = fmaf(x_s[r][k], w0, acc0[r]);
                    acc1[r] = fmaf(x_s[r][k], w1, acc1[r]);
                }
            }
            gate_accum_f32(acc0, acc1, &h_s[0][0][0], Whh0, j0, j1, HID, 0);
#pragma unroll
            for (int r = 0; r < BTF; ++r) { g_s[r][j0] = acc0[r]; g_s[r][j1] = acc1[r]; }
        }
        __syncthreads();
#pragma unroll
        for (int p = 0; p < 2; ++p) {
            int task = tid + p * NTH;
            int n = task & (HID - 1), r = task >> 8;
            float gi = g_s[r][n], gf = g_s[r][HID + n], gg = g_s[r][2 * HID + n], go = g_s[r][3 * HID + n];
            float c = sigf(gf) * c_s[0][r][n] + sigf(gi) * tanhfast(gg);
            float h = sigf(go) * tanhfast(c);
            c_s[0][r][n] = c; h_s[0][r][n] = h;
        }
        __syncthreads();
#pragma unroll
        for (int l = 1; l <= 2; ++l) {
            const float* WihD = WihL + (size_t)(l - 1) * G4 * (INSZ + HID);
            const float* WhhD = WhhL + (size_t)(l - 1) * G4 * HID;
            float acc0[BTF], acc1[BTF];
            float bb0 = bihL[(l - 1) * G4 + j0] + bhhL[(l - 1) * G4 + j0];
            float bb1 = bihL[(l - 1) * G4 + j1] + bhhL[(l - 1) * G4 + j1];
#pragma unroll
            for (int r = 0; r < BTF; ++r) { acc0[r] = bb0; acc1[r] = bb1; }
#pragma unroll
            for (int k = 0; k < INSZ; ++k) {
                float w0 = WihD[j0 * (INSZ + HID) + k], w1 = WihD[j1 * (INSZ + HID) + k];
#pragma unroll
                for (int r = 0; r < BTF; ++r) {
                    acc0[r] = fmaf(x_s[r][k], w0, acc0[r]);
                    acc1[r] = fmaf(x_s[r][k], w1, acc1[r]);
                }
            }
            gate_accum_f32(acc0, acc1, &h_s[l - 1][0][0], WihD, j0, j1, INSZ + HID, INSZ);
            gate_accum_f32(acc0, acc1, &h_s[l][0][0],     WhhD, j0, j1, HID, 0);
#pragma unroll
            for (int r = 0; r < BTF; ++r) { g_s[r][j0] = acc0[r]; g_s[r][j1] = acc1[r]; }
            __syncthreads();
#pragma unroll
            for (int p = 0; p < 2; ++p) {
                int task = tid + p * NTH;
                int n = task & (HID - 1), r = task >> 8;
                float gi = g_s[r][n], gf = g_s[r][HID + n], gg = g_s[r][2 * HID + n], go = g_s[r][3 * HID + n];
                float c = sigf(gf) * c_s[l][r][n] + sigf(gi) * tanhfast(gg);
                float h = sigf(go) * tanhfast(c);
                c_s[l][r][n] = c; h_s[l][r][n] = h;
            }
            __syncthreads();
        }
        if (tid < BTF * (NOUT + NW)) {
            int r  = tid / (NOUT + NW);
            int jo = tid - r * (NOUT + NW);
            const float* Wrow; float acc;
            if (jo < NOUT) { Wrow = Wg + (size_t)jo * (INSZ + HID); acc = bg[jo]; }
            else           { Wrow = Ww + (size_t)(jo - NOUT) * (INSZ + HID); acc = bw[jo - NOUT]; }
            acc = fmaf(x_s[r][0], Wrow[0], acc);
            acc = fmaf(x_s[r][1], Wrow[1], acc);
            const float* hr = &h_s[2][r][0];
#pragma unroll 4
            for (int k = 0; k < HID; k += 2) {
                float2 w2 = *reinterpret_cast<const float2*>(Wrow + INSZ + k);
                float2 h2 = *reinterpret_cast<const float2*>(hr + k);
                acc = fmaf(h2.x, w2.x, acc);
                acc = fmaf(h2.y, w2.y, acc);
            }
            if (jo < NOUT) out[((size_t)(b0 + r) * T_STEPS + t) * NOUT + jo] = acc;
            else           wl_s[r][jo - NOUT] = acc;
        }
        __syncthreads();
        if (tid < BTF) {
            int r = tid;
            float mx = -1e30f;
#pragma unroll
            for (int m = 0; m < NW; ++m) mx = fmaxf(mx, wl_s[r][m]);
            float e[NW]; float ssum = 0.0f;
#pragma unroll
            for (int m = 0; m < NW; ++m) { e[m] = __expf(wl_s[r][m] - mx); ssum += e[m]; }
            float inv = 1.0f / ssum;
            size_t base = GOFF + ((size_t)(b0 + r) * T_STEPS + t) * NW;
#pragma unroll
            for (int m = 0; m < NW; ++m) out[base + m] = e[m] * inv;
        }
        __syncthreads();
    }
}

extern "C" void kernel_launch(void* const* d_in, const int* in_sizes, int n_in,
                              void* d_out, int out_size, void* d_ws, size_t ws_size,
                              hipStream_t stream) {
    const float* x    = (const float*)d_in[0];
    const float* Wih0 = (const float*)d_in[1];
    const float* Whh0 = (const float*)d_in[2];
    const float* bih0 = (const float*)d_in[3];
    const float* bhh0 = (const float*)d_in[4];
    const float* WihL = (const float*)d_in[5];
    const float* WhhL = (const float*)d_in[6];
    const float* bihL = (const float*)d_in[7];
    const float* bhhL = (const float*)d_in[8];
    const float* Wg   = (const float*)d_in[9];
    const float* bg   = (const float*)d_in[10];
    const float* Ww   = (const float*)d_in[11];
    const float* bw   = (const float*)d_in[12];
    float* out = (float*)d_out;

    (void)in_sizes; (void)n_in; (void)out_size;

    if (ws_size >= (size_t)WS_DWORDS * 4) {
        uint32_t* wsd = (uint32_t*)d_ws;
        float*    wsf = (float*)d_ws;
        pack_w16<<<512, 256, 0, stream>>>(Whh0, wsd + OFF_P0, HID, 0);
        pack_w16<<<512, 256, 0, stream>>>(WihL, wsd + OFF_PI1, INSZ + HID, INSZ);
        pack_w16<<<512, 256, 0, stream>>>(WhhL, wsd + OFF_PH1, HID, 0);
        pack_w16<<<512, 256, 0, stream>>>(WihL + (size_t)G4 * (INSZ + HID), wsd + OFF_PI2, INSZ + HID, INSZ);
        pack_w16<<<512, 256, 0, stream>>>(WhhL + (size_t)G4 * HID,          wsd + OFF_PH2, HID, 0);
        xpart_t<<<8, 256, 0, stream>>>(Wih0, wsf + OFF_X,            INSZ);
        xpart_t<<<8, 256, 0, stream>>>(WihL, wsf + OFF_X + 2 * G4,   INSZ + HID);
        xpart_t<<<8, 256, 0, stream>>>(WihL + (size_t)G4 * (INSZ + HID), wsf + OFF_X + 4 * G4, INSZ + HID);
        add_vec<<<4, 256, 0, stream>>>(bih0, bhh0, wsf + OFF_B, G4);
        add_vec<<<4, 256, 0, stream>>>(bihL, bhhL, wsf + OFF_B + G4, G4);
        add_vec<<<4, 256, 0, stream>>>(bihL + G4, bhhL + G4, wsf + OFF_B + 2 * G4, G4);
        lstm_main16<<<BATCH / BT2, NTH, 0, stream>>>(x, Wg, bg, Ww, bw, wsd, out);
    } else {
        lstm_main_f32<<<BATCH / BTF, NTH, 0, stream>>>(
            x, Wih0, Whh0, bih0, bhh0, WihL, WhhL, bihL, bhhL, Wg, bg, Ww, bw, out);
    }
}